// Round 9
// baseline (93.812 us; speedup 1.0000x reference)
//
#include <hip/hip_runtime.h>
#include <cstdint>

typedef _Float16 f16x8 __attribute__((ext_vector_type(8)));
typedef _Float16 f16x4 __attribute__((ext_vector_type(4)));
typedef float    f32x4 __attribute__((ext_vector_type(4)));

static constexpr int TB = 2;
static constexpr int TT = 2048;
static constexpr int TE = 768;
static constexpr int TH = 12;
static constexpr int TD = 64;
static constexpr int TM = TB * TT;      // 4096 rows (B*T)
static constexpr int TK = TE;           // 768 (K for both GEMMs)
static constexpr int NQKV = 3 * TE;     // 2304

#define SCALE_LOG2E 0.18033688011112042f  /* (1/sqrt(64)) * log2(e) */

// async global->LDS, 16B per lane. LDS dest is wave-uniform base + lane*16.
__device__ __forceinline__ void gload16(const void* g, void* lds) {
  __builtin_amdgcn_global_load_lds(
      (__attribute__((address_space(1))) void*)(uintptr_t)g,
      (__attribute__((address_space(3))) void*)(uint32_t)(uintptr_t)lds, 16, 0, 0);
}

// ---------------------------------------------------------------------------
// f32 -> f16 convert. x -> row-major f16. w_qkv / w_final -> FRAGMENT-NATIVE
// Wf layout: f16 idx(n,k) = ((n>>4)*24 + (k>>5))*512 + ((k>>3)&3)*128
//                           + (n&15)*8 + (k&7)
// so a GEMM B-fragment (ni,kc) is 1KB contiguous, lane byte = lane*16.
// ---------------------------------------------------------------------------
__global__ void cvt3(const float* __restrict__ x, const float* __restrict__ wq,
                     const float* __restrict__ wf, _Float16* __restrict__ xh,
                     _Float16* __restrict__ wqh, _Float16* __restrict__ wfh) {
  const int NX = TM * TK / 4, NW = NQKV * TK / 4;
  int i = blockIdx.x * 256 + threadIdx.x;
  if (i < NX) {
    float4 v = ((const float4*)x)[i];
    f16x4 o = {(_Float16)v.x, (_Float16)v.y, (_Float16)v.z, (_Float16)v.w};
    *(f16x4*)&xh[(size_t)i * 4] = o;
  } else {
    const float4* src; _Float16* dst; int j;
    if (i < NX + NW) { src = (const float4*)wq; dst = wqh; j = i - NX; }
    else             { src = (const float4*)wf; dst = wfh; j = i - NX - NW; }
    float4 v = src[j];
    f16x4 o = {(_Float16)v.x, (_Float16)v.y, (_Float16)v.z, (_Float16)v.w};
    const int flat = j * 4;
    const int n = flat / TK, k = flat % TK;
    const size_t idx = ((size_t)(n >> 4) * 24 + (k >> 5)) * 512 +
                       ((k >> 3) & 3) * 128 + (n & 15) * 8 + (k & 7);
    *(f16x4*)&dst[idx] = o;
  }
}

// ---------------------------------------------------------------------------
// NT GEMM: C[M,N] = A[M,K] * Wf[N,K]^T (+bias). 128x128 tile, BK=64,
// 8 waves (512 thr), wave grid 2x4 (64x32 out each).
// A: LDS double-buffer (2x16KB), all 8 waves stage 2 chunks, gload16,
//    counted vmcnt + raw s_barrier.
// B: fragment-native global -> REGISTER double-buffer (bA/bB), loads issued
//    one K-step early (flow across the barrier; full-step latency cover).
// EPI=0: qkv epilogue (Q pre-scaled [B,H,T,D]; K',V' fragment-native).
// EPI=1: plain f32 out.
// ---------------------------------------------------------------------------
template <int EPI, int NXT>
__global__ __launch_bounds__(512)
void gemm_nt(const _Float16* __restrict__ A, const _Float16* __restrict__ Bw,
             const float* __restrict__ bias,
             _Float16* __restrict__ qb, _Float16* __restrict__ kb,
             _Float16* __restrict__ vtb, float* __restrict__ outp) {
  __shared__ _Float16 As[2][128 * 64];
  const int tid = threadIdx.x;
  const int w = tid >> 6, lane = tid & 63;
  const int lr = lane & 15, lk = lane >> 4;

  const int id = blockIdx.x;
  const int xcd = id & 7, j = id >> 3;
  const int m0 = (xcd * 4 + j / NXT) * 128;  // 4 M-panels per XCD
  const int n0 = (j % NXT) * 128;
  const int wr = w >> 2, wc = w & 3;  // 2x4 wave grid; wave = 64x32 out

  f32x4 acc[4][2] = {};
  const char* Ab = (const char*)(A + (size_t)m0 * TK);
  const char* WB = (const char*)Bw;
  const int nb = (n0 >> 4) + wc * 2;
  constexpr int NS = TK / 64;  // 12 K-steps

  auto loadB = [&](int ks, f16x8 (&bf)[2][2]) {
#pragma unroll
    for (int ni = 0; ni < 2; ++ni)
#pragma unroll
      for (int kc = 0; kc < 2; ++kc)
        bf[ni][kc] = *(const f16x8*)(WB +
                                     ((size_t)(nb + ni) * 24 + ks * 2 + kc) * 1024 +
                                     lane * 16);
  };
  auto stageA = [&](int ks, int buf) {
#pragma unroll
    for (int c = 0; c < 2; ++c) {
      int g = w * 2 + c;  // chunk 0..15 of the 16 KB A tile
      int o = g * 1024 + lane * 16;
      int row = o >> 7, ch = (o >> 4) & 7;
      gload16(Ab + (size_t)row * (TK * 2) + ks * 128 + ((ch ^ (row & 7)) << 4),
              (char*)As[buf] + g * 1024);
    }
  };
  auto step = [&](f16x8 (&bc)[2][2], f16x8 (&bn)[2][2], int buf, int ks) {
    if (ks + 1 < NS) {
      loadB(ks + 1, bn);      // 4 reg loads, consumed next step
      stageA(ks + 1, buf ^ 1);  // 2 gload16
      asm volatile("s_waitcnt vmcnt(6)" ::: "memory");  // cur A+B landed
    } else {
      asm volatile("s_waitcnt vmcnt(0)" ::: "memory");
    }
    __builtin_amdgcn_s_barrier();
#pragma unroll
    for (int kc = 0; kc < 2; ++kc) {
      f16x8 af[4];
#pragma unroll
      for (int mi = 0; mi < 4; ++mi) {
        int row = wr * 64 + mi * 16 + lr;
        af[mi] =
            *(const f16x8*)&As[buf][row * 64 + (((kc * 4 + lk) ^ (row & 7)) << 3)];
      }
#pragma unroll
      for (int mi = 0; mi < 4; ++mi)
#pragma unroll
        for (int ni = 0; ni < 2; ++ni)
          acc[mi][ni] = __builtin_amdgcn_mfma_f32_16x16x32_f16(af[mi], bc[ni][kc],
                                                               acc[mi][ni], 0, 0, 0);
    }
    __builtin_amdgcn_s_barrier();  // all reads of As[buf] done before restage
  };

  f16x8 bA[2][2], bB[2][2];
  loadB(0, bA);
  stageA(0, 0);
  for (int kss = 0; kss < NS; kss += 2) {
    step(bA, bB, 0, kss);
    step(bB, bA, 1, kss + 1);
  }

  // epilogue: C layout col = lane&15 (N), row = (lane>>4)*4 + r
#pragma unroll
  for (int mi = 0; mi < 4; ++mi) {
#pragma unroll
    for (int ni = 0; ni < 2; ++ni) {
      const int col = n0 + wc * 32 + ni * 16 + lr;
#pragma unroll
      for (int r = 0; r < 4; ++r) {
        const int row = m0 + wr * 64 + mi * 16 + lk * 4 + r;
        float v = acc[mi][ni][r];
        if (EPI == 0) {
          v += bias[col];
          const int which = (col >= 2 * TE) ? 2 : (col >= TE ? 1 : 0);
          const int e = col - which * TE;
          const int h = e >> 6, d = e & 63;
          const int b = row >> 11, t = row & (TT - 1);
          const size_t hb = (size_t)(b * TH + h);
          if (which == 0) {
            qb[(hb * TT + t) * TD + d] = (_Float16)(v * SCALE_LOG2E);
          } else if (which == 1) {
            // K' fragment-native
            kb[((((hb * 128 + (t >> 4)) * 8 + (d >> 3)) * 16 + (t & 15)) * 8) +
               (d & 7)] = (_Float16)v;
          } else {
            // V' fragment-native
            const int kc = (t >> 5) & 1, hi = (t >> 4) & 1;
            const int lkv = (t >> 2) & 3, m = t & 3;
            vtb[((((((hb * 32 + (t >> 6)) * 4 + (d >> 4)) * 2 + kc) * 4 + lkv) *
                      16 +
                  (d & 15)) *
                 8) +
                (hi * 4 + m)] = (_Float16)v;
          }
        } else {
          outp[(size_t)row * TE + col] = v;
        }
      }
    }
  }
}

// ---------------------------------------------------------------------------
// Causal flash attention, BARRIER-FREE, NO LDS. Grid 768 = 24 heads x 32
// 64-row q-tiles (bh=id%24, qt=31-id/24: balanced per CU, heavy first).
// 2 waves/block (128 thr); EACH WAVE OWNS 32 q-rows (two 16-row groups) so
// one 16KB KV tile load feeds 32 MFMAs (2x arithmetic intensity vs R7).
// K,V fragment-native global -> coalesced 1KB wave loads to VGPR; kfA/kfB
// register dbuf, K prefetched 2 tiles ahead, V issued at phase start.
// SWAPPED QK^T (mfma(K,Q)): lane-local softmax; P never leaves registers.
// T13 defer-max (thr=8, log2 domain), per group.
// ---------------------------------------------------------------------------
__global__ __launch_bounds__(128)
void attn_kernel(const _Float16* __restrict__ qbuf, const _Float16* __restrict__ kbuf,
                 const _Float16* __restrict__ vtbuf, _Float16* __restrict__ ob) {
  const int tid = threadIdx.x, w = tid >> 6, lane = tid & 63;
  const int lr = lane & 15, lk = lane >> 4;

  const int id = blockIdx.x;        // 0..767
  const int bh = id % 24;
  const int qt = 31 - id / 24;      // heavy first, balanced per CU
  const int t0 = qt * 64;
  const int nt = qt + 1, ntm1 = qt;
  const int q0 = t0 + w * 32;       // this wave's first q-row

  const _Float16* q = qbuf + (size_t)bh * (TT * TD);  // [T][64], pre-scaled
  const char* kbase =
      (const char*)(kbuf + (size_t)bh * (TT * TD)) + lk * 256 + lr * 16;
  const char* vbase =
      (const char*)(vtbuf + (size_t)bh * (TT * TD)) + lk * 256 + lr * 16;

  f16x8 qf0[2], qf1[2];  // B-operand: Q[q0+g*16+lr][kc*32+lk*8..]
#pragma unroll
  for (int kc = 0; kc < 2; ++kc) {
    qf0[kc] = *(const f16x8*)&q[(size_t)(q0 + lr) * TD + kc * 32 + lk * 8];
    qf1[kc] = *(const f16x8*)&q[(size_t)(q0 + 16 + lr) * TD + kc * 32 + lk * 8];
  }

  f32x4 of0[4] = {}, of1[4] = {};     // O[q=lk*4+r][d=nd*16+lr] per group
  float mr0 = -1e30f, ls0 = 0.f;      // softmax state, group 0 (q = lane&15)
  float mr1 = -1e30f, ls1 = 0.f;      // group 1

  f16x8 kfA[2][4], kfB[2][4], vf[2][4];

#pragma unroll
  for (int kc = 0; kc < 2; ++kc)
#pragma unroll
    for (int ni = 0; ni < 4; ++ni)
      kfA[kc][ni] = *(const f16x8*)(kbase + ni * 2048 + kc * 1024);
  {
    const char* k1 = kbase + (size_t)(nt > 1 ? 1 : 0) * 8192;
#pragma unroll
    for (int kc = 0; kc < 2; ++kc)
#pragma unroll
      for (int ni = 0; ni < 4; ++ni)
        kfB[kc][ni] = *(const f16x8*)(k1 + ni * 2048 + kc * 1024);
  }

  // mask + online softmax + pack + PV for one 16-q group
  auto sm_pv = [&](f32x4 (&sa)[4], float& mr, float& ls, f32x4 (&of_)[4],
                   int qb_, int s0, bool dia) {
    if (dia) {
#pragma unroll
      for (int ni = 0; ni < 4; ++ni)
#pragma unroll
        for (int r = 0; r < 4; ++r)
          if (s0 + ni * 16 + lk * 4 + r > qb_ + lr) sa[ni][r] = -1e30f;
    }
    float mx;
    {
      float a0 = fmaxf(fmaxf(sa[0][0], sa[0][1]), fmaxf(sa[0][2], sa[0][3]));
      float a1 = fmaxf(fmaxf(sa[1][0], sa[1][1]), fmaxf(sa[1][2], sa[1][3]));
      float a2 = fmaxf(fmaxf(sa[2][0], sa[2][1]), fmaxf(sa[2][2], sa[2][3]));
      float a3 = fmaxf(fmaxf(sa[3][0], sa[3][1]), fmaxf(sa[3][2], sa[3][3]));
      mx = fmaxf(fmaxf(a0, a1), fmaxf(a2, a3));
      mx = fmaxf(mx, __shfl_xor(mx, 16));
      mx = fmaxf(mx, __shfl_xor(mx, 32));
    }
    if (__any(mx > mr + 8.0f)) {  // defer-max
      float mn = fmaxf(mr, mx);
      float al = __builtin_amdgcn_exp2f(mr - mn);
      mr = mn;
      ls *= al;
      float al4[4];
#pragma unroll
      for (int r = 0; r < 4; ++r) al4[r] = __shfl(al, lk * 4 + r);
#pragma unroll
      for (int nd = 0; nd < 4; ++nd)
#pragma unroll
        for (int r = 0; r < 4; ++r) of_[nd][r] *= al4[r];
    }
    f16x8 pa[2];
    float rs;
    {
      float rn[4];
#pragma unroll
      for (int ni = 0; ni < 4; ++ni) {
        float p0 = __builtin_amdgcn_exp2f(sa[ni][0] - mr);
        float p1 = __builtin_amdgcn_exp2f(sa[ni][1] - mr);
        float p2 = __builtin_amdgcn_exp2f(sa[ni][2] - mr);
        float p3 = __builtin_amdgcn_exp2f(sa[ni][3] - mr);
        rn[ni] = (p0 + p1) + (p2 + p3);
        pa[ni >> 1][(ni & 1) * 4 + 0] = (_Float16)p0;
        pa[ni >> 1][(ni & 1) * 4 + 1] = (_Float16)p1;
        pa[ni >> 1][(ni & 1) * 4 + 2] = (_Float16)p2;
        pa[ni >> 1][(ni & 1) * 4 + 3] = (_Float16)p3;
      }
      rs = (rn[0] + rn[1]) + (rn[2] + rn[3]);
      rs += __shfl_xor(rs, 16);
      rs += __shfl_xor(rs, 32);
    }
    ls += rs;
    __builtin_amdgcn_s_setprio(1);
#pragma unroll
    for (int kc = 0; kc < 2; ++kc)
#pragma unroll
      for (int nd = 0; nd < 4; ++nd)
        of_[nd] =
            __builtin_amdgcn_mfma_f32_16x16x32_f16(pa[kc], vf[kc][nd], of_[nd], 0, 0, 0);
    __builtin_amdgcn_s_setprio(0);
  };

  auto phase = [&](f16x8 (&kf)[2][4], int st) {
    const char* vt = vbase + (size_t)st * 8192;  // V(st): cover = QK^T+softmax
#pragma unroll
    for (int kc = 0; kc < 2; ++kc)
#pragma unroll
      for (int nd = 0; nd < 4; ++nd)
        vf[kc][nd] = *(const f16x8*)(vt + nd * 2048 + kc * 1024);

    f32x4 sa0[4] = {}, sa1[4] = {};
    __builtin_amdgcn_s_setprio(1);
#pragma unroll
    for (int kc = 0; kc < 2; ++kc)
#pragma unroll
      for (int ni = 0; ni < 4; ++ni)
        sa0[ni] =
            __builtin_amdgcn_mfma_f32_16x16x32_f16(kf[kc][ni], qf0[kc], sa0[ni], 0, 0, 0);
#pragma unroll
    for (int kc = 0; kc < 2; ++kc)
#pragma unroll
      for (int ni = 0; ni < 4; ++ni)
        sa1[ni] =
            __builtin_amdgcn_mfma_f32_16x16x32_f16(kf[kc][ni], qf1[kc], sa1[ni], 0, 0, 0);
    __builtin_amdgcn_s_setprio(0);

    {  // prefetch K(st+2) into the buffer just consumed (clamped)
      const int stp = (st + 2 <= ntm1) ? st + 2 : ntm1;
      const char* kt = kbase + (size_t)stp * 8192;
#pragma unroll
      for (int kc = 0; kc < 2; ++kc)
#pragma unroll
        for (int ni = 0; ni < 4; ++ni)
          kf[kc][ni] = *(const f16x8*)(kt + ni * 2048 + kc * 1024);
    }

    const int s0 = st * 64;
    sm_pv(sa0, mr0, ls0, of0, q0, s0, s0 + 63 > q0);
    sm_pv(sa1, mr1, ls1, of1, q0 + 16, s0, s0 + 63 > q0 + 16);
  };

  int st = 0;
  while (st + 1 < nt) {
    phase(kfA, st);
    phase(kfB, st + 1);
    st += 2;
  }
  if (st < nt) phase(kfA, st);

  // epilogue per group: lrun owner lane lr = q (x4 replicas)
  const int b = bh / TH, h = bh - b * TH;
  {
    float linv[4];
#pragma unroll
    for (int r = 0; r < 4; ++r) linv[r] = __shfl(ls0, lk * 4 + r);
#pragma unroll
    for (int nd = 0; nd < 4; ++nd)
#pragma unroll
      for (int r = 0; r < 4; ++r) {
        int tg = q0 + lk * 4 + r;
        int d = nd * 16 + lr;
        ob[(size_t)(b * TT + tg) * TE + h * TD + d] = (_Float16)(of0[nd][r] / linv[r]);
      }
  }
  {
    float linv[4];
#pragma unroll
    for (int r = 0; r < 4; ++r) linv[r] = __shfl(ls1, lk * 4 + r);
#pragma unroll
    for (int nd = 0; nd < 4; ++nd)
#pragma unroll
      for (int r = 0; r < 4; ++r) {
        int tg = q0 + 16 + lk * 4 + r;
        int d = nd * 16 + lr;
        ob[(size_t)(b * TT + tg) * TE + h * TD + d] = (_Float16)(of1[nd][r] / linv[r]);
      }
  }
}

// ---------------------------------------------------------------------------
extern "C" void kernel_launch(void* const* d_in, const int* in_sizes, int n_in,
                              void* d_out, int out_size, void* d_ws, size_t ws_size,
                              hipStream_t stream) {
  const float* x    = (const float*)d_in[0];
  const float* wqkv = (const float*)d_in[1];
  const float* bqkv = (const float*)d_in[2];
  const float* wfin = (const float*)d_in[3];
  float* out = (float*)d_out;

  _Float16* xh  = (_Float16*)d_ws;          // [4096][768] row-major
  _Float16* wqh = xh + (size_t)TM * TK;     // fragment-native Wf
  _Float16* wfh = wqh + (size_t)NQKV * TK;  // fragment-native Wf
  _Float16* qb  = wfh + (size_t)TE * TE;    // [B,H,T,D] (pre-scaled)
  _Float16* kb  = qb + (size_t)TM * TE;     // K' fragment-native
  _Float16* vtb = kb + (size_t)TM * TE;     // V' fragment-native
  _Float16* ob  = vtb + (size_t)TM * TE;    // [4096][768] attn output

  cvt3<<<5376, 256, 0, stream>>>(x, wqkv, wfin, xh, wqh, wfh);
  gemm_nt<0, NQKV / 128><<<(NQKV / 128) * (TM / 128), 512, 0, stream>>>(
      xh, wqh, bqkv, qb, kb, vtb, nullptr);
  attn_kernel<<<dim3(TT / 64 * TB * TH), 128, 0, stream>>>(qb, kb, vtb, ob);
  gemm_nt<1, TE / 128><<<(TE / 128) * (TM / 128), 512, 0, stream>>>(
      ob, wfh, nullptr, nullptr, nullptr, nullptr, out);
}